// Round 21
// baseline (227.388 us; speedup 1.0000x reference)
//
#include <hip/hip_runtime.h>

typedef __bf16 bf16_t;
typedef __bf16 bf16x8 __attribute__((ext_vector_type(8)));
typedef __bf16 bf16x4 __attribute__((ext_vector_type(4)));
typedef float f32x4 __attribute__((ext_vector_type(4)));

static constexpr int Bb = 4, Hh = 12, Nn = 1024, Cc = 768, HD = 64;
static constexpr int OUT0 = Bb * Nn * Cc;  // 3145728 floats

#define GLD16(gp, lp)                                                       \
  __builtin_amdgcn_global_load_lds(                                         \
      (const __attribute__((address_space(1))) unsigned int*)(gp),          \
      (__attribute__((address_space(3))) unsigned int*)(lp), 16, 0, 0)

// ---------------- convert fp32 -> bf16 (x, qkv_w, proj_w) ----------------
__global__ __launch_bounds__(256) void convert_all(
    const float* __restrict__ x, const float* __restrict__ qw, const float* __restrict__ pw,
    bf16_t* __restrict__ xb, bf16_t* __restrict__ qwb, bf16_t* __restrict__ pwb) {
  const int NX = (Bb * Nn * Cc) / 4;  // 786432 float4s
  const int NQ = (3 * Cc * Cc) / 4;   // 442368
  int i = blockIdx.x * 256 + threadIdx.x;
  const float4* src;
  bf16_t* dst;
  int off;
  if (i < NX) { src = (const float4*)x; dst = xb; off = i; }
  else if (i < NX + NQ) { src = (const float4*)qw; dst = qwb; off = i - NX; }
  else { src = (const float4*)pw; dst = pwb; off = i - NX - NQ; }
  float4 v = src[off];
  bf16x4 o;
  o[0] = (bf16_t)v.x; o[1] = (bf16_t)v.y; o[2] = (bf16_t)v.z; o[3] = (bf16_t)v.w;
  *(bf16x4*)(dst + (size_t)off * 4) = o;
}

// ---------------- qkv GEMM: 128x128 tile, global_load_lds + XCD swizzle --
__global__ __launch_bounds__(256) void gemm_qkv(
    const bf16_t* __restrict__ A, const bf16_t* __restrict__ Bm,
    bf16_t* __restrict__ q_bf, bf16_t* __restrict__ k_bf, bf16_t* __restrict__ vT_bf) {
  __shared__ bf16_t As[128 * 32];  // linear (global_load_lds requirement)
  __shared__ bf16_t Bs[128 * 32];
  const int tid = threadIdx.x;
  const int lane = tid & 63;
  const int w = tid >> 6;
  const int wr = w >> 1, wc = w & 1;
  const int g = lane >> 4, r = lane & 15;
  const int bid2 = (blockIdx.x & 7) * 72 + (blockIdx.x >> 3);  // 576 = 8*72
  const int m0 = (bid2 / 18) << 7;
  const int n0 = (bid2 % 18) << 7;

  const f32x4 fz = {0.f, 0.f, 0.f, 0.f};
  f32x4 acc[4][4];
#pragma unroll
  for (int i = 0; i < 4; i++)
#pragma unroll
    for (int j = 0; j < 4; j++) acc[i][j] = fz;

  for (int k0 = 0; k0 < 768; k0 += 32) {
#pragma unroll
    for (int c = 0; c < 2; c++) {
      int row = w * 32 + c * 16 + (lane >> 2);
      int kof = (lane & 3) << 3;
      GLD16(&A[(size_t)(m0 + row) * 768 + k0 + kof], (char*)As + w * 2048 + c * 1024);
      GLD16(&Bm[(size_t)(n0 + row) * 768 + k0 + kof], (char*)Bs + w * 2048 + c * 1024);
    }
    __syncthreads();
    bf16x8 af[4], bfv[4];
#pragma unroll
    for (int i = 0; i < 4; i++) af[i] = *(const bf16x8*)&As[(wr * 64 + i * 16 + r) * 32 + g * 8];
#pragma unroll
    for (int j = 0; j < 4; j++) bfv[j] = *(const bf16x8*)&Bs[(wc * 64 + j * 16 + r) * 32 + g * 8];
#pragma unroll
    for (int i = 0; i < 4; i++)
#pragma unroll
      for (int j = 0; j < 4; j++)
        acc[i][j] = __builtin_amdgcn_mfma_f32_16x16x32_bf16(af[i], bfv[j], acc[i][j], 0, 0, 0);
    __syncthreads();
  }

#pragma unroll
  for (int i = 0; i < 4; i++) {
#pragma unroll
    for (int j = 0; j < 4; j++) {
      int c = n0 + wc * 64 + j * 16 + r;
#pragma unroll
      for (int e = 0; e < 4; e++) {
        int mrow = m0 + wr * 64 + i * 16 + g * 4 + e;
        float val = acc[i][j][e];
        int which = c / 768;
        int cc = c - which * 768;
        int h = cc >> 6, d = cc & 63;
        int b = mrow >> 10, n = mrow & 1023;
        size_t bh = (size_t)(b * Hh + h);
        if (which == 0)      q_bf[(bh * Nn + n) * HD + d] = (bf16_t)val;
        else if (which == 1) k_bf[(bh * Nn + n) * HD + d] = (bf16_t)val;
        else                 vT_bf[(bh * HD + d) * Nn + n] = (bf16_t)val;
      }
    }
  }
}

// ---------------- proj GEMM: 64x128 tiles, grid 384, XCD swizzle ---------
__global__ __launch_bounds__(256) void gemm_proj64(
    const bf16_t* __restrict__ A, const bf16_t* __restrict__ Bm,
    float* __restrict__ outF, const float* __restrict__ bias) {
  __shared__ bf16_t As[64 * 40];
  __shared__ bf16_t Bs[128 * 40];
  const int tid = threadIdx.x, lane = tid & 63, w = tid >> 6;
  const int wr = w >> 1, wc = w & 1;
  const int g = lane >> 4, r = lane & 15;
  const int bid2 = (blockIdx.x & 7) * 48 + (blockIdx.x >> 3);  // 384 = 8*48
  const int m0 = (bid2 / 6) << 6;
  const int n0 = (bid2 % 6) << 7;
  const f32x4 fz = {0.f, 0.f, 0.f, 0.f};
  f32x4 acc[2][4];
#pragma unroll
  for (int i = 0; i < 2; i++)
#pragma unroll
    for (int j = 0; j < 4; j++) acc[i][j] = fz;

  for (int k0 = 0; k0 < 768; k0 += 32) {
    {
      int row = tid >> 2, kof = (tid & 3) << 3;
      *(bf16x8*)&As[row * 40 + kof] = *(const bf16x8*)&A[(size_t)(m0 + row) * 768 + k0 + kof];
    }
#pragma unroll
    for (int p = 0; p < 2; p++) {
      int idx = tid + (p << 8);
      int row = idx >> 2, kof = (idx & 3) << 3;
      *(bf16x8*)&Bs[row * 40 + kof] = *(const bf16x8*)&Bm[(size_t)(n0 + row) * 768 + k0 + kof];
    }
    __syncthreads();
    bf16x8 af[2], bfv[4];
#pragma unroll
    for (int i = 0; i < 2; i++) af[i] = *(const bf16x8*)&As[(wr * 32 + i * 16 + r) * 40 + g * 8];
#pragma unroll
    for (int j = 0; j < 4; j++) bfv[j] = *(const bf16x8*)&Bs[(wc * 64 + j * 16 + r) * 40 + g * 8];
#pragma unroll
    for (int i = 0; i < 2; i++)
#pragma unroll
      for (int j = 0; j < 4; j++)
        acc[i][j] = __builtin_amdgcn_mfma_f32_16x16x32_bf16(af[i], bfv[j], acc[i][j], 0, 0, 0);
    __syncthreads();
  }

#pragma unroll
  for (int i = 0; i < 2; i++)
#pragma unroll
    for (int j = 0; j < 4; j++) {
      int c = n0 + wc * 64 + j * 16 + r;
#pragma unroll
      for (int e = 0; e < 4; e++) {
        int mrow = m0 + wr * 32 + i * 16 + g * 4 + e;
        outF[(size_t)mrow * 768 + c] = acc[i][j][e] + bias[c];
      }
    }
}

// ---------------- bias MLP, 32 rows/block --------------------------------
__global__ __launch_bounds__(256) void bias_mlp(
    const bf16_t* __restrict__ qb, const bf16_t* __restrict__ kb,
    const float* __restrict__ w1, const float* __restrict__ b1,
    const float* __restrict__ w2, const float* __restrict__ b2,
    float* __restrict__ bias4) {
  __shared__ float w1s[32 * 130];
  __shared__ float qks[8][128];
  __shared__ float h1s[8][32];
  const int t = threadIdx.x;
#pragma unroll
  for (int p = 0; p < 16; p++) {
    int idx = p * 256 + t;
    w1s[(idx >> 7) * 130 + (idx & 127)] = w1[idx];
  }
  const int rl = t >> 5, u = t & 31;
  const float b1u = b1[u];
  for (int ro = 0; ro < 4; ro++) {
    const int rowg = blockIdx.x * 32 + ro * 8 + rl;
    {
      int i4 = u * 4;
      const bf16_t* src = (i4 < 64) ? (qb + (size_t)rowg * HD + i4)
                                    : (kb + (size_t)rowg * HD + (i4 - 64));
      bf16x4 vv = *(const bf16x4*)src;
#pragma unroll
      for (int z = 0; z < 4; z++) qks[rl][i4 + z] = (float)vv[z];
    }
    __syncthreads();
    float accv = b1u;
#pragma unroll 16
    for (int i2 = 0; i2 < 64; i2++) {
      float2 wv = *(const float2*)&w1s[u * 130 + i2 * 2];
      float2 qv = *(const float2*)&qks[rl][i2 * 2];
      accv += wv.x * qv.x + wv.y * qv.y;
    }
    h1s[rl][u] = fmaxf(accv, 0.f);
    __syncthreads();
    if (u < 4) {
      float outv = 0.f;
      if (u < 3) {
        float s = b2[u];
#pragma unroll
        for (int j = 0; j < 32; j++) s += w2[u * 32 + j] * h1s[rl][j];
        float v = fabsf(s);
        outv = (u == 0) ? (1.f + v) : ((u == 1) ? v : -v * (1.f / (float)Nn));
      }
      bias4[(size_t)rowg * 4 + u] = outv;
    }
    __syncthreads();
  }
}

// ---------------- fused attn: split-PV, BOTH prev halves DMA-overlapped --
// 256 thr (4 waves); 32 rows/block. Phases:
//  1 QK(both rgs) + rg0-prev DMA (16x1KB/wave -> Plb as staging)
//  2 softmax + redsum barrier (drains DMA)
//  3 rg0 blend from LDS -> nb0 regs; __syncthreads
//  4 issue rg1-prev DMA (8x1KB/wave -> upper 32KB); write P0 (rows 0-15);
//    lgkmcnt + RAW s_barrier (DMA stays in flight)
//  5 PV-rg0 (rows 0-15, no alias with staging) + cur0 stores
//  6 blend rg1: staged 0-7 from LDS; ping-pong DMA 8-15 into same slots
//    (covered by blend VALU); barrier
//  7 write P1 (rows 16-31, overwrites staging); barrier
//  8 PV-rg1 + cur1 stores
__global__ __launch_bounds__(256, 2) void attn_fused(
    const bf16_t* __restrict__ qb, const bf16_t* __restrict__ kb,
    const bf16_t* __restrict__ vT, const float* __restrict__ prev,
    const float* __restrict__ bias4, float* __restrict__ cur,
    bf16_t* __restrict__ oh) {
  __shared__ char Plb[32 * 2048];   // 64KB: staging, then bf16 P
  __shared__ float redsum[32][4];
  const int bid = blockIdx.x;
  const int tile = (bid & 7) * 192 + (bid >> 3);  // XCD-bijective (1536%8==0)
  const int bh = tile >> 5, mt = tile & 31;
  const int tid = threadIdx.x;
  const int lane = tid & 63, w = tid >> 6;
  const int g = lane >> 4, r = lane & 15;
  const int row0 = mt << 5;
  const int cbase = w << 8;

  // ---- Phase 1: QK^T (swapped) + rg0 prev DMA into Plb ------------------
  const bf16_t* qp = qb + ((size_t)bh * Nn + row0) * HD;
  const bf16_t* kp = kb + (size_t)bh * Nn * HD;
  const float* ppr0 = prev + (size_t)bh * Nn * Nn + (size_t)(row0 + r) * Nn + cbase + (g << 2);
  const float* ppr1 = prev + (size_t)bh * Nn * Nn + (size_t)(row0 + 16 + r) * Nn + cbase + (g << 2);
  char* myPrev = Plb + (w << 14);       // wave-private 16KB (phase 1-3)
  char* stg = Plb + 32768 + (w << 13);  // wave-private 8KB (phase 4-6)
  bf16x8 q00 = *(const bf16x8*)&qp[r * HD + g * 8];
  bf16x8 q01 = *(const bf16x8*)&qp[r * HD + g * 8 + 32];
  bf16x8 q10 = *(const bf16x8*)&qp[(16 + r) * HD + g * 8];
  bf16x8 q11 = *(const bf16x8*)&qp[(16 + r) * HD + g * 8 + 32];
  bf16x8 qa0, qa1, qb0, qb1;
#pragma unroll
  for (int j = 0; j < 8; j++) {
    qa0[j] = (bf16_t)((float)q00[j] * 0.125f);
    qa1[j] = (bf16_t)((float)q01[j] * 0.125f);
    qb0[j] = (bf16_t)((float)q10[j] * 0.125f);
    qb1[j] = (bf16_t)((float)q11[j] * 0.125f);
  }
  const f32x4 fz = {0.f, 0.f, 0.f, 0.f};
  f32x4 acc0[16], acc1[16];
#pragma unroll
  for (int t = 0; t < 16; t++) {
    GLD16(ppr0 + (t << 4), myPrev + (t << 10));  // rg0 prev DMA
    int col = cbase + (t << 4) + r;
    bf16x8 kf0 = *(const bf16x8*)&kp[(size_t)col * HD + g * 8];
    bf16x8 kf1 = *(const bf16x8*)&kp[(size_t)col * HD + g * 8 + 32];
    f32x4 z0 = __builtin_amdgcn_mfma_f32_16x16x32_bf16(kf0, qa0, fz, 0, 0, 0);
    acc0[t] = __builtin_amdgcn_mfma_f32_16x16x32_bf16(kf1, qa1, z0, 0, 0, 0);
    f32x4 z1 = __builtin_amdgcn_mfma_f32_16x16x32_bf16(kf0, qb0, fz, 0, 0, 0);
    acc1[t] = __builtin_amdgcn_mfma_f32_16x16x32_bf16(kf1, qb1, z1, 0, 0, 0);
  }

  // ---- Phase 2: no-max softmax ------------------------------------------
  float sj0 = 0.f, sj1 = 0.f;
  bf16x4 p0[16], p1[16];
#pragma unroll
  for (int t = 0; t < 16; t++) {
    float a0 = __expf(fminf(acc0[t][0], 30.f)), a1 = __expf(fminf(acc0[t][1], 30.f));
    float a2 = __expf(fminf(acc0[t][2], 30.f)), a3 = __expf(fminf(acc0[t][3], 30.f));
    sj0 += (a0 + a1) + (a2 + a3);
    p0[t][0] = (bf16_t)a0; p0[t][1] = (bf16_t)a1;
    p0[t][2] = (bf16_t)a2; p0[t][3] = (bf16_t)a3;
    float b0v = __expf(fminf(acc1[t][0], 30.f)), b1v = __expf(fminf(acc1[t][1], 30.f));
    float b2v = __expf(fminf(acc1[t][2], 30.f)), b3v = __expf(fminf(acc1[t][3], 30.f));
    sj1 += (b0v + b1v) + (b2v + b3v);
    p1[t][0] = (bf16_t)b0v; p1[t][1] = (bf16_t)b1v;
    p1[t][2] = (bf16_t)b2v; p1[t][3] = (bf16_t)b3v;
  }
  sj0 += __shfl_xor(sj0, 16, 64);
  sj0 += __shfl_xor(sj0, 32, 64);
  sj1 += __shfl_xor(sj1, 16, 64);
  sj1 += __shfl_xor(sj1, 32, 64);
  if (lane < 16) {
    redsum[lane][w] = sj0;
    redsum[16 + lane][w] = sj1;
  }
  __syncthreads();  // drains rg0 prev DMA too
  const float inv0 =
      1.f / (redsum[r][0] + redsum[r][1] + redsum[r][2] + redsum[r][3]);
  const float inv1 =
      1.f / (redsum[16 + r][0] + redsum[16 + r][1] + redsum[16 + r][2] + redsum[16 + r][3]);

  // ---- Phase 3: rg0 blend from LDS-staged prev --------------------------
  const float4 bv0 = *(const float4*)&bias4[((size_t)bh * 1024 + row0 + r) * 4];
  const float4 bv1 = *(const float4*)&bias4[((size_t)bh * 1024 + row0 + 16 + r) * 4];
  bf16x4 nb0[16];
#pragma unroll
  for (int t = 0; t < 16; t++) {
    f32x4 pvv = *(const f32x4*)(myPrev + (t << 10) + (lane << 4));
    nb0[t][0] = (bf16_t)(bv0.x * ((float)p0[t][0] * inv0) + bv0.y * pvv[0] + bv0.z);
    nb0[t][1] = (bf16_t)(bv0.x * ((float)p0[t][1] * inv0) + bv0.y * pvv[1] + bv0.z);
    nb0[t][2] = (bf16_t)(bv0.x * ((float)p0[t][2] * inv0) + bv0.y * pvv[2] + bv0.z);
    nb0[t][3] = (bf16_t)(bv0.x * ((float)p0[t][3] * inv0) + bv0.y * pvv[3] + bv0.z);
  }
  __syncthreads();  // all staged-prev reads done before any P write

  // ---- Phase 4: rg1 DMA (tiles 0-7) + write P0; raw barrier -------------
#pragma unroll
  for (int t = 0; t < 8; t++) GLD16(ppr1 + (t << 4), stg + (t << 10));
#pragma unroll
  for (int t = 0; t < 16; t++) {
    int col = cbase + (t << 4) + (g << 2);
    int off = (r * 2048 + col * 2) ^ ((r & 7) << 4);
    *(bf16x4*)(Plb + off) = nb0[t];
  }
  asm volatile("s_waitcnt lgkmcnt(0)" ::: "memory");
  __builtin_amdgcn_sched_barrier(0);
  __builtin_amdgcn_s_barrier();  // P0 visible; DMA stays in flight

  // ---- Phase 5: PV-rg0 (rows 0-15) + cur0 stores ------------------------
  const bf16_t* vrow = vT + (size_t)bh * HD * Nn + (size_t)((w << 4) + r) * Nn;
  float* cp0 = cur + (size_t)bh * Nn * Nn + (size_t)(row0 + r) * Nn + cbase + (g << 2);
  float* cp1 = cur + (size_t)bh * Nn * Nn + (size_t)(row0 + 16 + r) * Nn + cbase + (g << 2);
  f32x4 o0q0 = fz, o0q1 = fz, o0q2 = fz, o0q3 = fz;
#pragma unroll
  for (int ks = 0; ks < 8; ks++) {
#pragma unroll
    for (int q = 0; q < 4; q++) {
      int i = ks * 4 + q;
      if (i < 16) {
        float4 p;
        p.x = (float)p0[i][0] * inv0;
        p.y = (float)p0[i][1] * inv0;
        p.z = (float)p0[i][2] * inv0;
        p.w = (float)p0[i][3] * inv0;
        *(float4*)&cp0[i << 4] = p;
      }
      int k0 = (q << 8) + (ks << 5);
      bf16x8 vb = *(const bf16x8*)&vrow[k0 + g * 8];
      bf16x8 pa0 = *(const bf16x8*)(Plb + ((r * 2048 + (k0 + g * 8) * 2) ^ ((r & 7) << 4)));
      if (q == 0) o0q0 = __builtin_amdgcn_mfma_f32_16x16x32_bf16(pa0, vb, o0q0, 0, 0, 0);
      else if (q == 1) o0q1 = __builtin_amdgcn_mfma_f32_16x16x32_bf16(pa0, vb, o0q1, 0, 0, 0);
      else if (q == 2) o0q2 = __builtin_amdgcn_mfma_f32_16x16x32_bf16(pa0, vb, o0q2, 0, 0, 0);
      else o0q3 = __builtin_amdgcn_mfma_f32_16x16x32_bf16(pa0, vb, o0q3, 0, 0, 0);
    }
  }
  f32x4 os0 = (o0q0 + o0q1) + (o0q2 + o0q3);

  // ---- Phase 6: rg1 blend (staged 0-7; ping-pong DMA 8-15) --------------
  asm volatile("s_waitcnt vmcnt(0)" ::: "memory");  // DMA 0-7 landed
  __builtin_amdgcn_sched_barrier(0);
  f32x4 pvv0[8];
#pragma unroll
  for (int t = 0; t < 8; t++)
    pvv0[t] = *(const f32x4*)(stg + (t << 10) + (lane << 4));
  asm volatile("s_waitcnt lgkmcnt(0)" ::: "memory");  // slots free
  __builtin_amdgcn_sched_barrier(0);
#pragma unroll
  for (int t = 0; t < 8; t++) GLD16(ppr1 + ((t + 8) << 4), stg + (t << 10));
  bf16x4 nb1[16];
#pragma unroll
  for (int t = 0; t < 8; t++) {  // blend 0-7 (covers DMA flight)
    nb1[t][0] = (bf16_t)(bv1.x * ((float)p1[t][0] * inv1) + bv1.y * pvv0[t][0] + bv1.z);
    nb1[t][1] = (bf16_t)(bv1.x * ((float)p1[t][1] * inv1) + bv1.y * pvv0[t][1] + bv1.z);
    nb1[t][2] = (bf16_t)(bv1.x * ((float)p1[t][2] * inv1) + bv1.y * pvv0[t][2] + bv1.z);
    nb1[t][3] = (bf16_t)(bv1.x * ((float)p1[t][3] * inv1) + bv1.y * pvv0[t][3] + bv1.z);
  }
  asm volatile("s_waitcnt vmcnt(0)" ::: "memory");  // DMA 8-15 landed
  __builtin_amdgcn_sched_barrier(0);
#pragma unroll
  for (int t = 8; t < 16; t++) {
    f32x4 pvv = *(const f32x4*)(stg + ((t - 8) << 10) + (lane << 4));
    nb1[t][0] = (bf16_t)(bv1.x * ((float)p1[t][0] * inv1) + bv1.y * pvv[0] + bv1.z);
    nb1[t][1] = (bf16_t)(bv1.x * ((float)p1[t][1] * inv1) + bv1.y * pvv[1] + bv1.z);
    nb1[t][2] = (bf16_t)(bv1.x * ((float)p1[t][2] * inv1) + bv1.y * pvv[2] + bv1.z);
    nb1[t][3] = (bf16_t)(bv1.x * ((float)p1[t][3] * inv1) + bv1.y * pvv[3] + bv1.z);
  }
  asm volatile("s_waitcnt lgkmcnt(0)" ::: "memory");
  __builtin_amdgcn_sched_barrier(0);
  __builtin_amdgcn_s_barrier();  // all staged reads done before P1 writes

  // ---- Phase 7: write P1 (rows 16-31) -----------------------------------
#pragma unroll
  for (int t = 0; t < 16; t++) {
    int col = cbase + (t << 4) + (g << 2);
    int off = ((16 + r) * 2048 + col * 2) ^ ((r & 7) << 4);
    *(bf16x4*)(Plb + off) = nb1[t];
  }
  asm volatile("s_waitcnt lgkmcnt(0)" ::: "memory");
  __builtin_amdgcn_sched_barrier(0);
  __builtin_amdgcn_s_barrier();  // P1 visible

  // ---- Phase 8: PV-rg1 (rows 16-31) + cur1 stores -----------------------
  f32x4 o1q0 = fz, o1q1 = fz, o1q2 = fz, o1q3 = fz;
#pragma unroll
  for (int ks = 0; ks < 8; ks++) {
#pragma unroll
    for (int q = 0; q < 4; q++) {
      int i = ks * 4 + q;
      if (i < 16) {
        float4 p;
        p.x = (float)p1[i][0] * inv1;
        p.y = (float)p1[i][1] * inv1;
        p.z = (float)p1[i][2] * inv1;
        p.w = (float)p1[i][3] * inv1;
        *(float4*)&cp1[i << 4] = p;
      }
      int k0 = (q << 8) + (ks << 5);
      bf16x8 vb = *(const bf16x8*)&vrow[k0 + g * 8];
      bf16x8 pa1 = *(const bf16x8*)(Plb + (((16 + r) * 2048 + (k0 + g * 8) * 2) ^ ((r & 7) << 4)));
      if (q == 0) o1q0 = __builtin_amdgcn_mfma_f32_16x16x32_bf16(pa1, vb, o1q0, 0, 0, 0);
      else if (q == 1) o1q1 = __builtin_amdgcn_mfma_f32_16x16x32_bf16(pa1, vb, o1q1, 0, 0, 0);
      else if (q == 2) o1q2 = __builtin_amdgcn_mfma_f32_16x16x32_bf16(pa1, vb, o1q2, 0, 0, 0);
      else o1q3 = __builtin_amdgcn_mfma_f32_16x16x32_bf16(pa1, vb, o1q3, 0, 0, 0);
    }
  }
  f32x4 os1 = (o1q0 + o1q1) + (o1q2 + o1q3);
  const int b = bh / Hh, h = bh % Hh;
#pragma unroll
  for (int e = 0; e < 4; e++) {
    int nrow = row0 + g * 4 + e;
    oh[((size_t)(b * Nn + nrow)) * Cc + h * HD + (w << 4) + r] = (bf16_t)os0[e];
    oh[((size_t)(b * Nn + nrow + 16)) * Cc + h * HD + (w << 4) + r] = (bf16_t)os1[e];
  }
}

// -------------------------------------------------------------------------
extern "C" void kernel_launch(void* const* d_in, const int* in_sizes, int n_in,
                              void* d_out, int out_size, void* d_ws, size_t ws_size,
                              hipStream_t stream) {
  const float* x      = (const float*)d_in[0];
  const float* prev   = (const float*)d_in[1];
  const float* qkv_w  = (const float*)d_in[2];
  const float* proj_w = (const float*)d_in[3];
  const float* proj_b = (const float*)d_in[4];
  const float* bp_w1  = (const float*)d_in[5];
  const float* bp_b1  = (const float*)d_in[6];
  const float* bp_w2  = (const float*)d_in[7];
  const float* bp_w2b = (const float*)d_in[8];

  float* out0 = (float*)d_out;
  float* cur  = out0 + OUT0;

  char* ws = (char*)d_ws;
  bf16_t* xb    = (bf16_t*)(ws + 0);
  bf16_t* qwb   = (bf16_t*)(ws + 6291456);
  bf16_t* pwb   = (bf16_t*)(ws + 9830400);
  bf16_t* qbf   = (bf16_t*)(ws + 11010048);
  bf16_t* kbf   = (bf16_t*)(ws + 17301504);
  bf16_t* vtb   = (bf16_t*)(ws + 23592960);
  float*  bias4 = (float*)(ws + 29884416);
  bf16_t* ohb   = (bf16_t*)(ws + 30670848);
  if (ws_size < 36962304) return;

  convert_all<<<5376, 256, 0, stream>>>(x, qkv_w, proj_w, xb, qwb, pwb);
  gemm_qkv<<<32 * 18, 256, 0, stream>>>(xb, qwb, qbf, kbf, vtb);
  bias_mlp<<<1536, 256, 0, stream>>>(qbf, kbf, bp_w1, bp_b1, bp_w2, bp_w2b, bias4);
  attn_fused<<<1536, 256, 0, stream>>>(qbf, kbf, vtb, prev, bias4, cur, ohb);
  gemm_proj64<<<64 * 6, 256, 0, stream>>>(ohb, pwb, out0, proj_b);
}

// Round 22
// 209.438 us; speedup vs baseline: 1.0857x; 1.0857x over previous
//
#include <hip/hip_runtime.h>

typedef __bf16 bf16_t;
typedef __bf16 bf16x8 __attribute__((ext_vector_type(8)));
typedef __bf16 bf16x4 __attribute__((ext_vector_type(4)));
typedef float f32x4 __attribute__((ext_vector_type(4)));

static constexpr int Bb = 4, Hh = 12, Nn = 1024, Cc = 768, HD = 64;
static constexpr int OUT0 = Bb * Nn * Cc;  // 3145728 floats

#define GLD16(gp, lp)                                                       \
  __builtin_amdgcn_global_load_lds(                                         \
      (const __attribute__((address_space(1))) unsigned int*)(gp),          \
      (__attribute__((address_space(3))) unsigned int*)(lp), 16, 0, 0)

// ---------------- convert fp32 -> bf16 (x, qkv_w, proj_w) ----------------
__global__ __launch_bounds__(256) void convert_all(
    const float* __restrict__ x, const float* __restrict__ qw, const float* __restrict__ pw,
    bf16_t* __restrict__ xb, bf16_t* __restrict__ qwb, bf16_t* __restrict__ pwb) {
  const int NX = (Bb * Nn * Cc) / 4;  // 786432 float4s
  const int NQ = (3 * Cc * Cc) / 4;   // 442368
  int i = blockIdx.x * 256 + threadIdx.x;
  const float4* src;
  bf16_t* dst;
  int off;
  if (i < NX) { src = (const float4*)x; dst = xb; off = i; }
  else if (i < NX + NQ) { src = (const float4*)qw; dst = qwb; off = i - NX; }
  else { src = (const float4*)pw; dst = pwb; off = i - NX - NQ; }
  float4 v = src[off];
  bf16x4 o;
  o[0] = (bf16_t)v.x; o[1] = (bf16_t)v.y; o[2] = (bf16_t)v.z; o[3] = (bf16_t)v.w;
  *(bf16x4*)(dst + (size_t)off * 4) = o;
}

// ---------------- qkv GEMM: 128x128 tile, global_load_lds + XCD swizzle --
__global__ __launch_bounds__(256) void gemm_qkv(
    const bf16_t* __restrict__ A, const bf16_t* __restrict__ Bm,
    bf16_t* __restrict__ q_bf, bf16_t* __restrict__ k_bf, bf16_t* __restrict__ vT_bf) {
  __shared__ bf16_t As[128 * 32];  // linear (global_load_lds requirement)
  __shared__ bf16_t Bs[128 * 32];
  const int tid = threadIdx.x;
  const int lane = tid & 63;
  const int w = tid >> 6;
  const int wr = w >> 1, wc = w & 1;
  const int g = lane >> 4, r = lane & 15;
  const int bid2 = (blockIdx.x & 7) * 72 + (blockIdx.x >> 3);  // 576 = 8*72
  const int m0 = (bid2 / 18) << 7;
  const int n0 = (bid2 % 18) << 7;

  const f32x4 fz = {0.f, 0.f, 0.f, 0.f};
  f32x4 acc[4][4];
#pragma unroll
  for (int i = 0; i < 4; i++)
#pragma unroll
    for (int j = 0; j < 4; j++) acc[i][j] = fz;

  for (int k0 = 0; k0 < 768; k0 += 32) {
#pragma unroll
    for (int c = 0; c < 2; c++) {
      int row = w * 32 + c * 16 + (lane >> 2);
      int kof = (lane & 3) << 3;
      GLD16(&A[(size_t)(m0 + row) * 768 + k0 + kof], (char*)As + w * 2048 + c * 1024);
      GLD16(&Bm[(size_t)(n0 + row) * 768 + k0 + kof], (char*)Bs + w * 2048 + c * 1024);
    }
    __syncthreads();
    bf16x8 af[4], bfv[4];
#pragma unroll
    for (int i = 0; i < 4; i++) af[i] = *(const bf16x8*)&As[(wr * 64 + i * 16 + r) * 32 + g * 8];
#pragma unroll
    for (int j = 0; j < 4; j++) bfv[j] = *(const bf16x8*)&Bs[(wc * 64 + j * 16 + r) * 32 + g * 8];
#pragma unroll
    for (int i = 0; i < 4; i++)
#pragma unroll
      for (int j = 0; j < 4; j++)
        acc[i][j] = __builtin_amdgcn_mfma_f32_16x16x32_bf16(af[i], bfv[j], acc[i][j], 0, 0, 0);
    __syncthreads();
  }

#pragma unroll
  for (int i = 0; i < 4; i++) {
#pragma unroll
    for (int j = 0; j < 4; j++) {
      int c = n0 + wc * 64 + j * 16 + r;
#pragma unroll
      for (int e = 0; e < 4; e++) {
        int mrow = m0 + wr * 64 + i * 16 + g * 4 + e;
        float val = acc[i][j][e];
        int which = c / 768;
        int cc = c - which * 768;
        int h = cc >> 6, d = cc & 63;
        int b = mrow >> 10, n = mrow & 1023;
        size_t bh = (size_t)(b * Hh + h);
        if (which == 0)      q_bf[(bh * Nn + n) * HD + d] = (bf16_t)val;
        else if (which == 1) k_bf[(bh * Nn + n) * HD + d] = (bf16_t)val;
        else                 vT_bf[(bh * HD + d) * Nn + n] = (bf16_t)val;
      }
    }
  }
}

// ---------------- proj GEMM: 64x128 tiles, grid 384, XCD swizzle ---------
__global__ __launch_bounds__(256) void gemm_proj64(
    const bf16_t* __restrict__ A, const bf16_t* __restrict__ Bm,
    float* __restrict__ outF, const float* __restrict__ bias) {
  __shared__ bf16_t As[64 * 40];
  __shared__ bf16_t Bs[128 * 40];
  const int tid = threadIdx.x, lane = tid & 63, w = tid >> 6;
  const int wr = w >> 1, wc = w & 1;
  const int g = lane >> 4, r = lane & 15;
  const int bid2 = (blockIdx.x & 7) * 48 + (blockIdx.x >> 3);  // 384 = 8*48
  const int m0 = (bid2 / 6) << 6;
  const int n0 = (bid2 % 6) << 7;
  const f32x4 fz = {0.f, 0.f, 0.f, 0.f};
  f32x4 acc[2][4];
#pragma unroll
  for (int i = 0; i < 2; i++)
#pragma unroll
    for (int j = 0; j < 4; j++) acc[i][j] = fz;

  for (int k0 = 0; k0 < 768; k0 += 32) {
    {
      int row = tid >> 2, kof = (tid & 3) << 3;
      *(bf16x8*)&As[row * 40 + kof] = *(const bf16x8*)&A[(size_t)(m0 + row) * 768 + k0 + kof];
    }
#pragma unroll
    for (int p = 0; p < 2; p++) {
      int idx = tid + (p << 8);
      int row = idx >> 2, kof = (idx & 3) << 3;
      *(bf16x8*)&Bs[row * 40 + kof] = *(const bf16x8*)&Bm[(size_t)(n0 + row) * 768 + k0 + kof];
    }
    __syncthreads();
    bf16x8 af[2], bfv[4];
#pragma unroll
    for (int i = 0; i < 2; i++) af[i] = *(const bf16x8*)&As[(wr * 32 + i * 16 + r) * 40 + g * 8];
#pragma unroll
    for (int j = 0; j < 4; j++) bfv[j] = *(const bf16x8*)&Bs[(wc * 64 + j * 16 + r) * 40 + g * 8];
#pragma unroll
    for (int i = 0; i < 2; i++)
#pragma unroll
      for (int j = 0; j < 4; j++)
        acc[i][j] = __builtin_amdgcn_mfma_f32_16x16x32_bf16(af[i], bfv[j], acc[i][j], 0, 0, 0);
    __syncthreads();
  }

#pragma unroll
  for (int i = 0; i < 2; i++)
#pragma unroll
    for (int j = 0; j < 4; j++) {
      int c = n0 + wc * 64 + j * 16 + r;
#pragma unroll
      for (int e = 0; e < 4; e++) {
        int mrow = m0 + wr * 32 + i * 16 + g * 4 + e;
        outF[(size_t)mrow * 768 + c] = acc[i][j][e] + bias[c];
      }
    }
}

// ---------------- bias MLP, 32 rows/block --------------------------------
__global__ __launch_bounds__(256) void bias_mlp(
    const bf16_t* __restrict__ qb, const bf16_t* __restrict__ kb,
    const float* __restrict__ w1, const float* __restrict__ b1,
    const float* __restrict__ w2, const float* __restrict__ b2,
    float* __restrict__ bias4) {
  __shared__ float w1s[32 * 130];
  __shared__ float qks[8][128];
  __shared__ float h1s[8][32];
  const int t = threadIdx.x;
#pragma unroll
  for (int p = 0; p < 16; p++) {
    int idx = p * 256 + t;
    w1s[(idx >> 7) * 130 + (idx & 127)] = w1[idx];
  }
  const int rl = t >> 5, u = t & 31;
  const float b1u = b1[u];
  for (int ro = 0; ro < 4; ro++) {
    const int rowg = blockIdx.x * 32 + ro * 8 + rl;
    {
      int i4 = u * 4;
      const bf16_t* src = (i4 < 64) ? (qb + (size_t)rowg * HD + i4)
                                    : (kb + (size_t)rowg * HD + (i4 - 64));
      bf16x4 vv = *(const bf16x4*)src;
#pragma unroll
      for (int z = 0; z < 4; z++) qks[rl][i4 + z] = (float)vv[z];
    }
    __syncthreads();
    float accv = b1u;
#pragma unroll 16
    for (int i2 = 0; i2 < 64; i2++) {
      float2 wv = *(const float2*)&w1s[u * 130 + i2 * 2];
      float2 qv = *(const float2*)&qks[rl][i2 * 2];
      accv += wv.x * qv.x + wv.y * qv.y;
    }
    h1s[rl][u] = fmaxf(accv, 0.f);
    __syncthreads();
    if (u < 4) {
      float outv = 0.f;
      if (u < 3) {
        float s = b2[u];
#pragma unroll
        for (int j = 0; j < 32; j++) s += w2[u * 32 + j] * h1s[rl][j];
        float v = fabsf(s);
        outv = (u == 0) ? (1.f + v) : ((u == 1) ? v : -v * (1.f / (float)Nn));
      }
      bias4[(size_t)rowg * 4 + u] = outv;
    }
    __syncthreads();
  }
}

// ---------------- fused attn: R20 winner (verbatim) ----------------------
// 256 thr (4 waves); 32 rows/block; wave w cols [256w,+256), 2 row-groups.
// QK phase also issues 16x1KB GLD16 of rg0's prev tile into Plb (idle
// then; zero VGPR dests -> genuinely in flight; drained by redsum barrier).
// Blend: rg0 from LDS (no HBM), nb0 in regs, barrier (cross-wave alias),
// then rg0 P-write + rg1 prev from HBM. cur stores interleaved into PV.
__global__ __launch_bounds__(256, 2) void attn_fused(
    const bf16_t* __restrict__ qb, const bf16_t* __restrict__ kb,
    const bf16_t* __restrict__ vT, const float* __restrict__ prev,
    const float* __restrict__ bias4, float* __restrict__ cur,
    bf16_t* __restrict__ oh) {
  __shared__ char Plb[32 * 2048];   // 64KB: prev-DMA staging, then bf16 P
  __shared__ float redsum[32][4];
  const int bid = blockIdx.x;
  const int tile = (bid & 7) * 192 + (bid >> 3);  // XCD-bijective (1536%8==0)
  const int bh = tile >> 5, mt = tile & 31;
  const int tid = threadIdx.x;
  const int lane = tid & 63, w = tid >> 6;
  const int g = lane >> 4, r = lane & 15;
  const int row0 = mt << 5;
  const int cbase = w << 8;

  // ---- QK^T (swapped) + rg0 prev DMA into Plb ---------------------------
  const bf16_t* qp = qb + ((size_t)bh * Nn + row0) * HD;
  const bf16_t* kp = kb + (size_t)bh * Nn * HD;
  const float* ppr0 = prev + (size_t)bh * Nn * Nn + (size_t)(row0 + r) * Nn + cbase + (g << 2);
  char* myPrev = Plb + (w << 14);  // wave-private 16KB (16 slots x 1KB)
  bf16x8 q00 = *(const bf16x8*)&qp[r * HD + g * 8];
  bf16x8 q01 = *(const bf16x8*)&qp[r * HD + g * 8 + 32];
  bf16x8 q10 = *(const bf16x8*)&qp[(16 + r) * HD + g * 8];
  bf16x8 q11 = *(const bf16x8*)&qp[(16 + r) * HD + g * 8 + 32];
  bf16x8 qa0, qa1, qb0, qb1;
#pragma unroll
  for (int j = 0; j < 8; j++) {
    qa0[j] = (bf16_t)((float)q00[j] * 0.125f);
    qa1[j] = (bf16_t)((float)q01[j] * 0.125f);
    qb0[j] = (bf16_t)((float)q10[j] * 0.125f);
    qb1[j] = (bf16_t)((float)q11[j] * 0.125f);
  }
  const f32x4 fz = {0.f, 0.f, 0.f, 0.f};
  f32x4 acc0[16], acc1[16];
#pragma unroll
  for (int t = 0; t < 16; t++) {
    GLD16(ppr0 + (t << 4), myPrev + (t << 10));  // rg0 prev DMA (no regs)
    int col = cbase + (t << 4) + r;
    bf16x8 kf0 = *(const bf16x8*)&kp[(size_t)col * HD + g * 8];
    bf16x8 kf1 = *(const bf16x8*)&kp[(size_t)col * HD + g * 8 + 32];
    f32x4 z0 = __builtin_amdgcn_mfma_f32_16x16x32_bf16(kf0, qa0, fz, 0, 0, 0);
    acc0[t] = __builtin_amdgcn_mfma_f32_16x16x32_bf16(kf1, qa1, z0, 0, 0, 0);
    f32x4 z1 = __builtin_amdgcn_mfma_f32_16x16x32_bf16(kf0, qb0, fz, 0, 0, 0);
    acc1[t] = __builtin_amdgcn_mfma_f32_16x16x32_bf16(kf1, qb1, z1, 0, 0, 0);
  }

  // ---- no-max softmax: sum of exp (clamped); pack P to bf16 -------------
  float sj0 = 0.f, sj1 = 0.f;
  bf16x4 p0[16], p1[16];
#pragma unroll
  for (int t = 0; t < 16; t++) {
    float a0 = __expf(fminf(acc0[t][0], 30.f)), a1 = __expf(fminf(acc0[t][1], 30.f));
    float a2 = __expf(fminf(acc0[t][2], 30.f)), a3 = __expf(fminf(acc0[t][3], 30.f));
    sj0 += (a0 + a1) + (a2 + a3);
    p0[t][0] = (bf16_t)a0; p0[t][1] = (bf16_t)a1;
    p0[t][2] = (bf16_t)a2; p0[t][3] = (bf16_t)a3;
    float b0v = __expf(fminf(acc1[t][0], 30.f)), b1v = __expf(fminf(acc1[t][1], 30.f));
    float b2v = __expf(fminf(acc1[t][2], 30.f)), b3v = __expf(fminf(acc1[t][3], 30.f));
    sj1 += (b0v + b1v) + (b2v + b3v);
    p1[t][0] = (bf16_t)b0v; p1[t][1] = (bf16_t)b1v;
    p1[t][2] = (bf16_t)b2v; p1[t][3] = (bf16_t)b3v;
  }
  sj0 += __shfl_xor(sj0, 16, 64);
  sj0 += __shfl_xor(sj0, 32, 64);
  sj1 += __shfl_xor(sj1, 16, 64);
  sj1 += __shfl_xor(sj1, 32, 64);
  if (lane < 16) {
    redsum[lane][w] = sj0;
    redsum[16 + lane][w] = sj1;
  }
  __syncthreads();  // drains rg0 prev DMA too
  const float inv0 =
      1.f / (redsum[r][0] + redsum[r][1] + redsum[r][2] + redsum[r][3]);
  const float inv1 =
      1.f / (redsum[16 + r][0] + redsum[16 + r][1] + redsum[16 + r][2] + redsum[16 + r][3]);

  // ---- rg0 blend from LDS-staged prev (no HBM) --------------------------
  const float4 bv0 = *(const float4*)&bias4[((size_t)bh * 1024 + row0 + r) * 4];
  const float4 bv1 = *(const float4*)&bias4[((size_t)bh * 1024 + row0 + 16 + r) * 4];
  bf16x4 nb0[16];
#pragma unroll
  for (int t = 0; t < 16; t++) {
    f32x4 pvv = *(const f32x4*)(myPrev + (t << 10) + (lane << 4));
    nb0[t][0] = (bf16_t)(bv0.x * ((float)p0[t][0] * inv0) + bv0.y * pvv[0] + bv0.z);
    nb0[t][1] = (bf16_t)(bv0.x * ((float)p0[t][1] * inv0) + bv0.y * pvv[1] + bv0.z);
    nb0[t][2] = (bf16_t)(bv0.x * ((float)p0[t][2] * inv0) + bv0.y * pvv[2] + bv0.z);
    nb0[t][3] = (bf16_t)(bv0.x * ((float)p0[t][3] * inv0) + bv0.y * pvv[3] + bv0.z);
  }
  __syncthreads();  // ALL prev-LDS reads done before ANY P write (alias)

  // ---- write rg0 P; rg1 blend from HBM ----------------------------------
#pragma unroll
  for (int t = 0; t < 16; t++) {
    int col = cbase + (t << 4) + (g << 2);
    int off = (r * 2048 + col * 2) ^ ((r & 7) << 4);
    *(bf16x4*)(Plb + off) = nb0[t];
  }
  {
    const float* ppr = prev + (size_t)bh * Nn * Nn + (size_t)(row0 + 16 + r) * Nn + cbase + (g << 2);
#pragma unroll
    for (int t = 0; t < 16; t++) {
      float4 pvv = *(const float4*)&ppr[t << 4];
      bf16x4 nb;
      nb[0] = (bf16_t)(bv1.x * ((float)p1[t][0] * inv1) + bv1.y * pvv.x + bv1.z);
      nb[1] = (bf16_t)(bv1.x * ((float)p1[t][1] * inv1) + bv1.y * pvv.y + bv1.z);
      nb[2] = (bf16_t)(bv1.x * ((float)p1[t][2] * inv1) + bv1.y * pvv.z + bv1.z);
      nb[3] = (bf16_t)(bv1.x * ((float)p1[t][3] * inv1) + bv1.y * pvv.w + bv1.z);
      int col = cbase + (t << 4) + (g << 2);
      int off = ((16 + r) * 2048 + col * 2) ^ ((r & 7) << 4);
      *(bf16x4*)(Plb + off) = nb;
    }
  }
  __syncthreads();

  // ---- PV with interleaved cur stores ------------------------------------
  const bf16_t* vrow = vT + (size_t)bh * HD * Nn + (size_t)((w << 4) + r) * Nn;
  float* cp0 = cur + (size_t)bh * Nn * Nn + (size_t)(row0 + r) * Nn + cbase + (g << 2);
  float* cp1 = cur + (size_t)bh * Nn * Nn + (size_t)(row0 + 16 + r) * Nn + cbase + (g << 2);
  f32x4 o0q0 = fz, o0q1 = fz, o0q2 = fz, o0q3 = fz;
  f32x4 o1q0 = fz, o1q1 = fz, o1q2 = fz, o1q3 = fz;
#pragma unroll
  for (int ks = 0; ks < 8; ks++) {
    int kA = ks << 5;
#pragma unroll
    for (int q = 0; q < 4; q++) {
      int i = ks * 4 + q;
      if (i < 16) {
        float4 p;
        p.x = (float)p0[i][0] * inv0;
        p.y = (float)p0[i][1] * inv0;
        p.z = (float)p0[i][2] * inv0;
        p.w = (float)p0[i][3] * inv0;
        *(float4*)&cp0[i << 4] = p;
      } else {
        int t = i - 16;
        float4 p;
        p.x = (float)p1[t][0] * inv1;
        p.y = (float)p1[t][1] * inv1;
        p.z = (float)p1[t][2] * inv1;
        p.w = (float)p1[t][3] * inv1;
        *(float4*)&cp1[t << 4] = p;
      }
      int k0 = (q << 8) + kA;
      bf16x8 vb = *(const bf16x8*)&vrow[k0 + g * 8];
      bf16x8 pa0 = *(const bf16x8*)(Plb + ((r * 2048 + (k0 + g * 8) * 2) ^ ((r & 7) << 4)));
      bf16x8 pa1 = *(const bf16x8*)(Plb + (((16 + r) * 2048 + (k0 + g * 8) * 2) ^ ((r & 7) << 4)));
      if (q == 0) {
        o0q0 = __builtin_amdgcn_mfma_f32_16x16x32_bf16(pa0, vb, o0q0, 0, 0, 0);
        o1q0 = __builtin_amdgcn_mfma_f32_16x16x32_bf16(pa1, vb, o1q0, 0, 0, 0);
      } else if (q == 1) {
        o0q1 = __builtin_amdgcn_mfma_f32_16x16x32_bf16(pa0, vb, o0q1, 0, 0, 0);
        o1q1 = __builtin_amdgcn_mfma_f32_16x16x32_bf16(pa1, vb, o1q1, 0, 0, 0);
      } else if (q == 2) {
        o0q2 = __builtin_amdgcn_mfma_f32_16x16x32_bf16(pa0, vb, o0q2, 0, 0, 0);
        o1q2 = __builtin_amdgcn_mfma_f32_16x16x32_bf16(pa1, vb, o1q2, 0, 0, 0);
      } else {
        o0q3 = __builtin_amdgcn_mfma_f32_16x16x32_bf16(pa0, vb, o0q3, 0, 0, 0);
        o1q3 = __builtin_amdgcn_mfma_f32_16x16x32_bf16(pa1, vb, o1q3, 0, 0, 0);
      }
    }
  }
  f32x4 os0 = (o0q0 + o0q1) + (o0q2 + o0q3);
  f32x4 os1 = (o1q0 + o1q1) + (o1q2 + o1q3);
  const int b = bh / Hh, h = bh % Hh;
#pragma unroll
  for (int e = 0; e < 4; e++) {
    int nrow = row0 + g * 4 + e;
    oh[((size_t)(b * Nn + nrow)) * Cc + h * HD + (w << 4) + r] = (bf16_t)os0[e];
    oh[((size_t)(b * Nn + nrow + 16)) * Cc + h * HD + (w << 4) + r] = (bf16_t)os1[e];
  }
}

// -------------------------------------------------------------------------
extern "C" void kernel_launch(void* const* d_in, const int* in_sizes, int n_in,
                              void* d_out, int out_size, void* d_ws, size_t ws_size,
                              hipStream_t stream) {
  const float* x      = (const float*)d_in[0];
  const float* prev   = (const float*)d_in[1];
  const float* qkv_w  = (const float*)d_in[2];
  const float* proj_w = (const float*)d_in[3];
  const float* proj_b = (const float*)d_in[4];
  const float* bp_w1  = (const float*)d_in[5];
  const float* bp_b1  = (const float*)d_in[6];
  const float* bp_w2  = (const float*)d_in[7];
  const float* bp_w2b = (const float*)d_in[8];

  float* out0 = (float*)d_out;
  float* cur  = out0 + OUT0;

  char* ws = (char*)d_ws;
  bf16_t* xb    = (bf16_t*)(ws + 0);
  bf16_t* qwb   = (bf16_t*)(ws + 6291456);
  bf16_t* pwb   = (bf16_t*)(ws + 9830400);
  bf16_t* qbf   = (bf16_t*)(ws + 11010048);
  bf16_t* kbf   = (bf16_t*)(ws + 17301504);
  bf16_t* vtb   = (bf16_t*)(ws + 23592960);
  float*  bias4 = (float*)(ws + 29884416);
  bf16_t* ohb   = (bf16_t*)(ws + 30670848);
  if (ws_size < 36962304) return;

  convert_all<<<5376, 256, 0, stream>>>(x, qkv_w, proj_w, xb, qwb, pwb);
  gemm_qkv<<<32 * 18, 256, 0, stream>>>(xb, qwb, qbf, kbf, vtb);
  bias_mlp<<<1536, 256, 0, stream>>>(qbf, kbf, bp_w1, bp_b1, bp_w2, bp_w2b, bias4);
  attn_fused<<<1536, 256, 0, stream>>>(qbf, kbf, vtb, prev, bias4, cur, ohb);
  gemm_proj64<<<64 * 6, 256, 0, stream>>>(ohb, pwb, out0, proj_b);
}